// Round 12
// baseline (394.458 us; speedup 1.0000x reference)
//
#include <hip/hip_runtime.h>
#include <math.h>

#define A_N 64
#define B_N 4096
#define D_N 50
#define H_N 192
#define O_N 3

typedef __attribute__((ext_vector_type(8))) __bf16 bf16x8;
typedef __attribute__((ext_vector_type(4))) __bf16 bf16x4;
typedef __attribute__((ext_vector_type(4))) float f32x4;

// ws (bf16 elems): only w1/s1 (K=50 needs zero-pad) and ow (N-pad) are pre-packed.
// frag elem (lane,j) = W[nt*16+(lane&15)][ks*32+(lane>>4)*8+j]
#define W1_OFF   0          // [A][12 nt][2 ks][512]   K=64 (padded from 50)
#define S1_OFF   786432
#define OW_OFF   1572864    // [A][6 ks][512]          N=16 (padded from 3), K=192
#define WS_ELEMS 1769472    // *2 B = 3.5 MB of d_ws

#if __has_builtin(__builtin_amdgcn_rcpf)
#define FRCP(x) __builtin_amdgcn_rcpf(x)
#else
#define FRCP(x) (1.0f / (x))
#endif
#if __has_builtin(__builtin_amdgcn_exp2f)
#define FEXP2(x) __builtin_amdgcn_exp2f(x)
#else
#define FEXP2(x) exp2f(x)
#endif

// A&S 7.1.26 erf (|eps|<=1.5e-7) + native rcp/exp2
__device__ __forceinline__ float gelu_f(float xx) {
    float t  = 0.70710678118654752440f * xx;
    float at = fabsf(t);
    float k  = FRCP(fmaf(0.3275911f, at, 1.0f));
    float p  = fmaf(k, 1.061405429f, -1.453152027f);
    p = fmaf(k, p, 1.421413741f);
    p = fmaf(k, p, -0.284496736f);
    p = fmaf(k, p, 0.254829592f);
    p = p * k;
    float e  = FEXP2(t * t * -1.44269504088896340736f);
    float er = fmaf(-p, e, 1.0f);
    er = (t < 0.f) ? -er : er;
    return 0.5f * xx * (1.0f + er);
}

// Tiny prep: w1/s1 via LDS transpose+pad (128 blocks), ow pad (12 blocks).
__global__ __launch_bounds__(256)
void prep_kernel(const float* __restrict__ w1, const float* __restrict__ s1,
                 const float* __restrict__ ow, __bf16* __restrict__ ws) {
    __shared__ __bf16 T[192 * 72];
    const int b   = blockIdx.x;
    const int tid = threadIdx.x;

    if (b < 128) {
        int m = b >> 6; int a = b & 63;
        const float* src = (m ? s1 : w1) + (size_t)a * 9600;
        __bf16* dst = ws + (m ? S1_OFF : W1_OFF) + (size_t)a * 12288;
        for (int e = tid; e < 192 * 72; e += 256) T[e] = (__bf16)0.f;
        __syncthreads();
        for (int e = tid; e < 9600; e += 256) {
            int row = e / 50, k = e - row * 50;
            T[row * 72 + k] = (__bf16)src[e];
        }
        __syncthreads();
        #pragma unroll
        for (int i = 0; i < 6; ++i) {                 // 1536 frag-rows (12 nt x 2 ks x 64)
            int fr = i * 256 + tid;
            int f = fr >> 6, lane = fr & 63;
            int nt = f >> 1, ks = f & 1;
            int n = nt * 16 + (lane & 15), k = ks * 32 + (lane >> 4) * 8;
            bf16x8 v = *(const bf16x8*)(T + n * 72 + k);
            *(bf16x8*)(dst + (size_t)(nt * 2 + ks) * 512 + lane * 8) = v;
        }
    } else {
        int r = b - 128;
        #pragma unroll
        for (int i = 0; i < 8; ++i) {                 // 24576 frag-rows total
            int fr = (r * 8 + i) * 256 + tid;
            int a = fr / 384, rem = fr - a * 384;
            int ks = rem >> 6, lane = rem & 63;
            int n = lane & 15, k = ks * 32 + (lane >> 4) * 8;
            bf16x8 v;
            if (n < O_N) {
                const float* p = ow + ((size_t)a * O_N + n) * H_N + k;
                f32x4 f0 = *(const f32x4*)p, f1 = *(const f32x4*)(p + 4);
                #pragma unroll
                for (int j = 0; j < 4; ++j) { v[j] = (__bf16)f0[j]; v[4 + j] = (__bf16)f1[j]; }
            } else {
                #pragma unroll
                for (int j = 0; j < 8; ++j) v[j] = (__bf16)0.f;
            }
            *(bf16x8*)(ws + OW_OFF + (size_t)a * 3072 + ks * 512 + lane * 8) = v;
        }
    }
}

// Operand-swapped MFMA: weights = A, activations = B.
// D: col(weight-col) = quad*4+reg, row(batch-row) = lane&15.
#define MFMA(a, b, c) __builtin_amdgcn_mfma_f32_16x16x32_bf16((a), (b), (c), 0, 0, 0)

// Block = 1 agent x 64 rows, 256 threads (4 waves). Wave wv owns cols [wv*48,wv*48+48).
// Dual GEMMs as TWO PASSES with in-place gelu transform (acc is the S-pass C operand).
// W2/S2/W3 fragments loaded ON THE FLY from row-major fp32 (2x f32x4 + cvt) — no prep
// round-trip. launch_bounds(256,3): reg cap ~168 -> no spill (round-9 lesson).
__global__ __launch_bounds__(256, 3)
void srek_mfma(const float* __restrict__ x,
               const float* __restrict__ inw, const float* __restrict__ inb,
               const float* __restrict__ b1,  const float* __restrict__ b2,
               const float* __restrict__ b3,  const float* __restrict__ s1b,
               const float* __restrict__ s2b, const float* __restrict__ hnw,
               const float* __restrict__ hnb, const float* __restrict__ ob,
               const float* __restrict__ w2f, const float* __restrict__ s2f,
               const float* __restrict__ w3f,
               const __bf16* __restrict__ ws, float* __restrict__ out) {
    __shared__ __bf16 Xs[64 * 72];    // x_norm (9.2 KB)
    __shared__ __bf16 Hs[64 * 200];   // h1 -> h2 -> h3 (25.6 KB); total 34.8 KB

    const int bid  = blockIdx.x;
    const int slot = bid >> 3;
    const int tile = slot & 63;
    const int a    = ((bid & 7) << 3) | (slot >> 6);   // agent pinned to XCD
    const int row0 = tile * 64;

    const int tid  = threadIdx.x;
    const int lane = tid & 63;
    const int wv   = tid >> 6;     // col-quarter
    const int ln   = lane & 15;
    const int quad = lane >> 4;
    const int aH   = a * H_N;
    const int c0   = wv * 48;
    const int l8   = lane * 8;
    const int f3   = wv * 3;       // this wave's nt base (3 disjoint col-tiles)

    const __bf16* W1 = ws + W1_OFF + (size_t)a * 12288;
    const __bf16* S1 = ws + S1_OFF + (size_t)a * 12288;
    const __bf16* OWp= ws + OW_OFF + (size_t)a * 3072;
    const float*  W2 = w2f + (size_t)a * 36864;
    const float*  S2 = s2f + (size_t)a * 36864;
    const float*  W3 = w3f + (size_t)a * 36864;

    bf16x8 nxt[3], cw[3], ow6[6];
    f32x4  nf[6];
    f32x4  acc[12];
    const f32x4 zero = {0.f, 0.f, 0.f, 0.f};

    // bf16 frag prefetch (L1 only, from ws)
    auto ldw3 = [&](const __bf16* base, int ks) {
        #pragma unroll
        for (int t = 0; t < 3; ++t)
            nxt[t] = *(const bf16x8*)(base + ((f3 + t) * 2 + ks) * 512 + l8);
    };
    auto take = [&]() {
        #pragma unroll
        for (int t = 0; t < 3; ++t) cw[t] = nxt[t];
    };
    // fp32 on-the-fly frag prefetch (W2/S2/W3): row nt*16+ln, cols ks*32+quad*8..+7
    auto ldw3f = [&](const float* base, int ks) {
        #pragma unroll
        for (int t = 0; t < 3; ++t) {
            const float* p = base + (size_t)((f3 + t) * 16 + ln) * 192 + ks * 32 + quad * 8;
            nf[2 * t]     = *(const f32x4*)p;
            nf[2 * t + 1] = *(const f32x4*)(p + 4);
        }
    };
    auto takef = [&]() {
        #pragma unroll
        for (int t = 0; t < 3; ++t)
            #pragma unroll
            for (int j = 0; j < 4; ++j) {
                cw[t][j]     = (__bf16)nf[2 * t][j];
                cw[t][4 + j] = (__bf16)nf[2 * t + 1][j];
            }
    };
    auto pass = [&](const __bf16* As, int pitch, int ks) {
        #pragma unroll
        for (int mt = 0; mt < 4; ++mt) {
            bf16x8 av = *(const bf16x8*)(As + (mt * 16 + ln) * pitch + ks * 32 + quad * 8);
            #pragma unroll
            for (int t = 0; t < 3; ++t)
                acc[mt * 3 + t] = MFMA(cw[t], av, acc[mt * 3 + t]);
        }
    };
    // acc <- gelu(acc + b) + sb   (in-place C-layout transform between passes)
    auto gelu_xform = [&](const float* bp, const float* sp) {
        #pragma unroll
        for (int t = 0; t < 3; ++t) {
            int colb = c0 + t * 16 + quad * 4;
            f32x4 bb = *(const f32x4*)(bp + aH + colb);
            f32x4 sb = *(const f32x4*)(sp + aH + colb);
            #pragma unroll
            for (int mt = 0; mt < 4; ++mt)
                #pragma unroll
                for (int rg = 0; rg < 4; ++rg)
                    acc[mt * 3 + t][rg] = gelu_f(acc[mt * 3 + t][rg] + bb[rg]) + sb[rg];
        }
    };
    auto store_acc_bf16 = [&]() {
        #pragma unroll
        for (int t = 0; t < 3; ++t) {
            int colb = c0 + t * 16 + quad * 4;
            #pragma unroll
            for (int mt = 0; mt < 4; ++mt) {
                bf16x4 o;
                #pragma unroll
                for (int rg = 0; rg < 4; ++rg) o[rg] = (__bf16)acc[mt * 3 + t][rg];
                *(bf16x4*)(Hs + (mt * 16 + ln) * 200 + colb) = o;
            }
        }
    };

    // prefetch L1 W ks0
    ldw3(W1, 0);

    // x_norm -> Xs (hides prefetch latency)
    for (int e = tid; e < 64 * 64; e += 256) {
        int r = e >> 6, k = e & 63;
        float v = 0.f;
        if (k < D_N) v = x[(size_t)(row0 + r) * D_N + k] * inw[a * D_N + k] + inb[a * D_N + k];
        Xs[r * 72 + k] = (__bf16)v;
    }
    #pragma unroll
    for (int i = 0; i < 12; ++i) acc[i] = zero;
    __syncthreads();                                   // B1: Xs ready

    // ===== layer1: T-pass (W1), gelu transform, S-pass (S1) =====
    take(); ldw3(W1, 1); pass(Xs, 72, 0);
    take(); ldw3(S1, 0); pass(Xs, 72, 1);
    gelu_xform(b1, s1b);
    take(); ldw3(S1, 1); pass(Xs, 72, 0);
    take(); ldw3f(W2, 0); pass(Xs, 72, 1);             // prefetch L2 ks0 (fp32 path)
    // acc == h1
    store_acc_bf16();                                  // Hs fresh: no pre-barrier needed
    #pragma unroll
    for (int i = 0; i < 12; ++i) acc[i] = zero;
    __syncthreads();                                   // B2: h1 ready

    // ===== layer2: T-pass (W2), gelu transform, S-pass (S2) =====
    #pragma unroll
    for (int ks = 0; ks < 6; ++ks) {
        takef();
        if (ks < 5) ldw3f(W2, ks + 1); else ldw3f(S2, 0);
        pass(Hs, 200, ks);
    }
    gelu_xform(b2, s2b);
    #pragma unroll
    for (int ks = 0; ks < 6; ++ks) {
        takef();
        if (ks < 5) ldw3f(S2, ks + 1); else ldw3f(W3, 0);
        pass(Hs, 200, ks);
    }
    // acc == h2 (fp32, stays live as the residual AND as layer-3's C operand)
    __syncthreads();                                   // B3: all h1 reads done
    store_acc_bf16();                                  // h2 -> Hs (bf16 operand copy)
    // fold b3 into acc (residual + bias become layer-3 C-init)
    #pragma unroll
    for (int t = 0; t < 3; ++t) {
        int colb = c0 + t * 16 + quad * 4;
        f32x4 b3v = *(const f32x4*)(b3 + aH + colb);
        #pragma unroll
        for (int mt = 0; mt < 4; ++mt)
            #pragma unroll
            for (int rg = 0; rg < 4; ++rg)
                acc[mt * 3 + t][rg] += b3v[rg];
    }
    __syncthreads();                                   // B4: h2 ready

    // ===== layer3 (K=192), C-init = h2 + b3 =====
    #pragma unroll
    for (int ks = 0; ks < 6; ++ks) {
        takef();
        if (ks < 5) ldw3f(W3, ks + 1);
        else {
            #pragma unroll
            for (int kk = 0; kk < 6; ++kk)             // prefetch OW frags (short live range)
                ow6[kk] = *(const bf16x8*)(OWp + kk * 512 + l8);
        }
        pass(Hs, 200, ks);
    }
    // h3 = acc*hnw + hnb
    #pragma unroll
    for (int t = 0; t < 3; ++t) {
        int colb = c0 + t * 16 + quad * 4;
        f32x4 nwv = *(const f32x4*)(hnw + aH + colb);
        f32x4 nbv = *(const f32x4*)(hnb + aH + colb);
        #pragma unroll
        for (int mt = 0; mt < 4; ++mt)
            #pragma unroll
            for (int rg = 0; rg < 4; ++rg)
                acc[mt * 3 + t][rg] = fmaf(acc[mt * 3 + t][rg], nwv[rg], nbv[rg]);
    }
    __syncthreads();                                   // B5: all h2 reads done
    store_acc_bf16();                                  // h3 -> Hs
    __syncthreads();                                   // B6: h3 ready

    // ===== output layer (wave wv = row-mtile wv) =====
    {
        f32x4 acco = zero;
        #pragma unroll
        for (int ks = 0; ks < 6; ++ks) {
            bf16x8 av = *(const bf16x8*)(Hs + (wv * 16 + ln) * 200 + ks * 32 + quad * 8);
            acco = MFMA(ow6[ks], av, acco);
        }
        if (quad == 0) {                               // o = rg (0..2), rows = wv*16+ln
            float* po = out + ((size_t)a * B_N + row0 + wv * 16 + ln) * O_N;
            po[0] = acco[0] + ob[a * O_N + 0];
            po[1] = acco[1] + ob[a * O_N + 1];
            po[2] = acco[2] + ob[a * O_N + 2];
        }
    }
}

extern "C" void kernel_launch(void* const* d_in, const int* in_sizes, int n_in,
                              void* d_out, int out_size, void* d_ws, size_t ws_size,
                              hipStream_t stream) {
    const float* x   = (const float*)d_in[0];
    const float* inw = (const float*)d_in[1];
    const float* inb = (const float*)d_in[2];
    const float* w1  = (const float*)d_in[3];
    const float* b1  = (const float*)d_in[4];
    const float* w2  = (const float*)d_in[5];
    const float* b2  = (const float*)d_in[6];
    const float* w3  = (const float*)d_in[7];
    const float* b3  = (const float*)d_in[8];
    const float* ow  = (const float*)d_in[9];
    const float* ob  = (const float*)d_in[10];
    const float* s1w = (const float*)d_in[11];
    const float* s1b = (const float*)d_in[12];
    const float* s2w = (const float*)d_in[13];
    const float* s2b = (const float*)d_in[14];
    const float* hnw = (const float*)d_in[15];
    const float* hnb = (const float*)d_in[16];

    __bf16* ws = (__bf16*)d_ws;   // 3.5 MB of d_ws

    prep_kernel<<<dim3(140), dim3(256), 0, stream>>>(w1, s1w, ow, ws);

    srek_mfma<<<dim3(A_N * (B_N / 64)), dim3(256), 0, stream>>>(
        x, inw, inb, b1, b2, b3, s1b, s2b, hnw, hnb, ob,
        w2, s2w, w3, ws, (float*)d_out);
}

// Round 14
// 226.317 us; speedup vs baseline: 1.7429x; 1.7429x over previous
//
#include <hip/hip_runtime.h>
#include <math.h>

#define A_N 64
#define B_N 4096
#define D_N 50
#define H_N 192
#define O_N 3

typedef __attribute__((ext_vector_type(8))) __bf16 bf16x8;
typedef __attribute__((ext_vector_type(4))) __bf16 bf16x4;
typedef __attribute__((ext_vector_type(4))) float f32x4;

// ws layout (bf16 elems), frag-packed: frag elem (lane,j) = W[nt*16+(lane&15)][ks*32+(lane>>4)*8+j]
#define W1_OFF   0          // [A][12 nt][2 ks][512]   K=64 (padded from 50)
#define S1_OFF   786432
#define W2_OFF   1572864    // [A][12 nt][6 ks][512]   K=192
#define S2_OFF   3932160
#define W3_OFF   6291456
#define OW_OFF   8650752    // [A][6 ks][512]          N=16 (padded from 3), K=192
#define WS_ELEMS 8847360    // *2 B = 17.7 MB of d_ws

#if __has_builtin(__builtin_amdgcn_rcpf)
#define FRCP(x) __builtin_amdgcn_rcpf(x)
#else
#define FRCP(x) (1.0f / (x))
#endif
#if __has_builtin(__builtin_amdgcn_exp2f)
#define FEXP2(x) __builtin_amdgcn_exp2f(x)
#else
#define FEXP2(x) exp2f(x)
#endif

// A&S 7.1.26 erf (|eps|<=1.5e-7) + native rcp/exp2
__device__ __forceinline__ float gelu_f(float xx) {
    float t  = 0.70710678118654752440f * xx;
    float at = fabsf(t);
    float k  = FRCP(fmaf(0.3275911f, at, 1.0f));
    float p  = fmaf(k, 1.061405429f, -1.453152027f);
    p = fmaf(k, p, 1.421413741f);
    p = fmaf(k, p, -0.284496736f);
    p = fmaf(k, p, 0.254829592f);
    p = p * k;
    float e  = FEXP2(t * t * -1.44269504088896340736f);
    float er = fmaf(-p, e, 1.0f);
    er = (t < 0.f) ? -er : er;
    return 0.5f * xx * (1.0f + er);
}

// Prep v3 (HW-validated in round 9): fine-grained blocks, 1 barrier each.
__global__ __launch_bounds__(256)
void prep_kernel(const float* __restrict__ w1, const float* __restrict__ s1,
                 const float* __restrict__ w2, const float* __restrict__ s2,
                 const float* __restrict__ w3, const float* __restrict__ ow,
                 __bf16* __restrict__ ws) {
    __shared__ __bf16 T[192 * 72];   // sec A uses [32][200] = 6400 of it
    const int b   = blockIdx.x;
    const int tid = threadIdx.x;

    if (b < 1152) {
        int m  = b / 384;                 // 0=w2 1=s2 2=w3
        int r  = b % 384;
        int a  = r / 6;
        int rc = r % 6;                   // 32-row chunk
        const float* src = ((m == 0) ? w2 : (m == 1) ? s2 : w3) + (size_t)a * 36864;
        __bf16* dst = ws + ((m == 0) ? W2_OFF : (m == 1) ? S2_OFF : W3_OFF) + (size_t)a * 36864;
        #pragma unroll
        for (int i = 0; i < 6; ++i) {                 // 1536 float4 = 32 rows x 192 cols
            int f4 = i * 256 + tid;
            int row = f4 / 48, kc = (f4 % 48) * 4;
            f32x4 v = *(const f32x4*)(src + (size_t)(rc * 32 + row) * 192 + kc);
            bf16x4 o;
            #pragma unroll
            for (int j = 0; j < 4; ++j) o[j] = (__bf16)v[j];
            *(bf16x4*)(T + row * 200 + kc) = o;       // pitch 200: 2-way max
        }
        __syncthreads();
        #pragma unroll
        for (int i = 0; i < 3; ++i) {                 // 768 frag-rows (2 nt x 6 ks x 64)
            int fr = i * 256 + tid;
            int f = fr >> 6, lane = fr & 63;
            int ntl = f / 6, ks = f % 6;
            int n = ntl * 16 + (lane & 15), k = ks * 32 + (lane >> 4) * 8;
            bf16x8 v = *(const bf16x8*)(T + n * 200 + k);
            *(bf16x8*)(dst + ((size_t)(rc * 2 + ntl) * 6 + ks) * 512 + lane * 8) = v;
        }
    } else if (b < 1280) {
        int r = b - 1152; int m = r >> 6; int a = r & 63;
        const float* src = (m ? s1 : w1) + (size_t)a * 9600;
        __bf16* dst = ws + (m ? S1_OFF : W1_OFF) + (size_t)a * 12288;
        for (int e = tid; e < 192 * 72; e += 256) T[e] = (__bf16)0.f;
        __syncthreads();
        for (int e = tid; e < 9600; e += 256) {
            int row = e / 50, k = e - row * 50;
            T[row * 72 + k] = (__bf16)src[e];
        }
        __syncthreads();
        #pragma unroll
        for (int i = 0; i < 6; ++i) {                 // 1536 frag-rows (12 nt x 2 ks x 64)
            int fr = i * 256 + tid;
            int f = fr >> 6, lane = fr & 63;
            int nt = f >> 1, ks = f & 1;
            int n = nt * 16 + (lane & 15), k = ks * 32 + (lane >> 4) * 8;
            bf16x8 v = *(const bf16x8*)(T + n * 72 + k);
            *(bf16x8*)(dst + (size_t)(nt * 2 + ks) * 512 + lane * 8) = v;
        }
    } else {
        int r = b - 1280;
        #pragma unroll
        for (int i = 0; i < 8; ++i) {                 // 24576 frag-rows total
            int fr = (r * 8 + i) * 256 + tid;
            int a = fr / 384, rem = fr - a * 384;
            int ks = rem >> 6, lane = rem & 63;
            int n = lane & 15, k = ks * 32 + (lane >> 4) * 8;
            bf16x8 v;
            if (n < O_N) {
                const float* p = ow + ((size_t)a * O_N + n) * H_N + k;
                f32x4 f0 = *(const f32x4*)p, f1 = *(const f32x4*)(p + 4);
                #pragma unroll
                for (int j = 0; j < 4; ++j) { v[j] = (__bf16)f0[j]; v[4 + j] = (__bf16)f1[j]; }
            } else {
                #pragma unroll
                for (int j = 0; j < 8; ++j) v[j] = (__bf16)0.f;
            }
            *(bf16x8*)(ws + OW_OFF + (size_t)a * 3072 + ks * 512 + lane * 8) = v;
        }
    }
}

// Operand-swapped MFMA: weights = A, activations = B.
// D: col(weight-col) = quad*4+reg, row(batch-row) = lane&15.
#define MFMA(a, b, c) __builtin_amdgcn_mfma_f32_16x16x32_bf16((a), (b), (c), 0, 0, 0)

// Round-5 structure (dual-acc, bf16 prepack) + FRAG-MAJOR activation LDS:
// Xs/Hs stored as [mt][ks][lane][8] so every A-read is uniform-base + lane*16B
// (zero bank conflicts; old [row][k] pitch-200 layout was 8-way conflicted:
//  bank = 4*(ln+quad)+j mod 32 for any 16B-aligned pitch).
__global__ __launch_bounds__(256, 3)
void srek_mfma(const float* __restrict__ x,
               const float* __restrict__ inw, const float* __restrict__ inb,
               const float* __restrict__ b1,  const float* __restrict__ b2,
               const float* __restrict__ b3,  const float* __restrict__ s1b,
               const float* __restrict__ s2b, const float* __restrict__ hnw,
               const float* __restrict__ hnb, const float* __restrict__ ob,
               const __bf16* __restrict__ ws, float* __restrict__ out) {
    __shared__ __bf16 Xs[8 * 512];    // x_norm frag-major [mt4][ks2][512] (8 KB)
    __shared__ __bf16 Hs[24 * 512];   // h1->h2->h3 frag-major [mt4][ks6][512] (24 KB)

    const int bid  = blockIdx.x;
    const int slot = bid >> 3;
    const int tile = slot & 63;
    const int a    = ((bid & 7) << 3) | (slot >> 6);   // agent pinned to XCD
    const int row0 = tile * 64;

    const int tid  = threadIdx.x;
    const int lane = tid & 63;
    const int wv   = tid >> 6;     // col-quarter
    const int ln   = lane & 15;
    const int quad = lane >> 4;
    const int aH   = a * H_N;
    const int c0   = wv * 48;
    const int l8   = lane * 8;
    const int f3   = wv * 3;       // this wave's nt base (3 disjoint col-tiles)

    const __bf16* W1 = ws + W1_OFF + (size_t)a * 12288;
    const __bf16* S1 = ws + S1_OFF + (size_t)a * 12288;
    const __bf16* W2 = ws + W2_OFF + (size_t)a * 36864;
    const __bf16* S2 = ws + S2_OFF + (size_t)a * 36864;
    const __bf16* W3 = ws + W3_OFF + (size_t)a * 36864;
    const __bf16* OWp= ws + OW_OFF + (size_t)a * 3072;

    bf16x8 nxt[6];
    f32x4 accT[12], accS[12], h2f[12];
    const f32x4 zero = {0.f, 0.f, 0.f, 0.f};

    // prefetch L1 ks0 (this wave's 3 W + 3 S frags)
    #pragma unroll
    for (int t = 0; t < 3; ++t) {
        nxt[t]     = *(const bf16x8*)(W1 + ((f3 + t) * 2 + 0) * 512 + l8);
        nxt[3 + t] = *(const bf16x8*)(S1 + ((f3 + t) * 2 + 0) * 512 + l8);
    }

    // x_norm -> Xs frag-major (hides prefetch latency)
    for (int e = tid; e < 8 * 512; e += 256) {
        int j   = e & 7;
        int lnn = (e >> 3) & 15;
        int qd  = (e >> 7) & 3;
        int kss = (e >> 9) & 1;
        int mtt = (e >> 10) & 3;
        int r = mtt * 16 + lnn;
        int k = kss * 32 + qd * 8 + j;
        float v = 0.f;
        if (k < D_N) v = x[(size_t)(row0 + r) * D_N + k] * inw[a * D_N + k] + inb[a * D_N + k];
        Xs[e] = (__bf16)v;
    }

    auto compute_dual = [&](const __bf16* As, int KS, int ks,
                            const bf16x8* cw, const bf16x8* cs) {
        #pragma unroll
        for (int mt = 0; mt < 4; ++mt) {
            bf16x8 av = *(const bf16x8*)(As + (mt * KS + ks) * 512 + l8);
            #pragma unroll
            for (int t = 0; t < 3; ++t) {
                accT[mt * 3 + t] = MFMA(cw[t], av, accT[mt * 3 + t]);
                accS[mt * 3 + t] = MFMA(cs[t], av, accS[mt * 3 + t]);
            }
        }
    };
    auto compute_single = [&](int ks, const bf16x8* cw) {
        #pragma unroll
        for (int mt = 0; mt < 4; ++mt) {
            bf16x8 av = *(const bf16x8*)(Hs + (mt * 6 + ks) * 512 + l8);
            #pragma unroll
            for (int t = 0; t < 3; ++t)
                accT[mt * 3 + t] = MFMA(cw[t], av, accT[mt * 3 + t]);
        }
    };
    // store 12 f32x4 (C-layout) into Hs frag-major as bf16
    auto store_fragmajor = [&](const f32x4* src) {
        #pragma unroll
        for (int t = 0; t < 3; ++t) {
            int ks2 = (3 * wv + t) >> 1;                       // (48wv+16t)>>5
            int qp  = (6 * wv + 2 * t + (quad >> 1)) & 3;      // chunk within frag
            int off = (qp * 16 + ln) * 8 + (quad & 1) * 4;     // 8B-aligned
            #pragma unroll
            for (int mt = 0; mt < 4; ++mt) {
                bf16x4 o;
                #pragma unroll
                for (int rg = 0; rg < 4; ++rg) o[rg] = (__bf16)src[mt * 3 + t][rg];
                *(bf16x4*)(Hs + (mt * 6 + ks2) * 512 + off) = o;
            }
        }
    };

    #pragma unroll
    for (int i = 0; i < 12; ++i) { accT[i] = zero; accS[i] = zero; }
    __syncthreads();                                   // B1: Xs ready

    // ================= layer1 + skip1 (K=64, 2 chunks) =================
    {
        bf16x8 cw[3], cs[3];
        #pragma unroll
        for (int t = 0; t < 3; ++t) { cw[t] = nxt[t]; cs[t] = nxt[3 + t]; }
        #pragma unroll
        for (int t = 0; t < 3; ++t) {                  // prefetch L1 ks1
            nxt[t]     = *(const bf16x8*)(W1 + ((f3 + t) * 2 + 1) * 512 + l8);
            nxt[3 + t] = *(const bf16x8*)(S1 + ((f3 + t) * 2 + 1) * 512 + l8);
        }
        compute_dual(Xs, 2, 0, cw, cs);
        #pragma unroll
        for (int t = 0; t < 3; ++t) { cw[t] = nxt[t]; cs[t] = nxt[3 + t]; }
        #pragma unroll
        for (int t = 0; t < 3; ++t) {                  // prefetch L2 ks0
            nxt[t]     = *(const bf16x8*)(W2 + ((f3 + t) * 6 + 0) * 512 + l8);
            nxt[3 + t] = *(const bf16x8*)(S2 + ((f3 + t) * 6 + 0) * 512 + l8);
        }
        compute_dual(Xs, 2, 1, cw, cs);
    }
    // epilogue L1: h1 = gelu(T+b1) + S + s1b -> Hs (fresh region)
    #pragma unroll
    for (int t = 0; t < 3; ++t) {
        int colb = c0 + t * 16 + quad * 4;
        f32x4 bb = *(const f32x4*)(b1 + aH + colb);
        f32x4 sb = *(const f32x4*)(s1b + aH + colb);
        #pragma unroll
        for (int mt = 0; mt < 4; ++mt)
            #pragma unroll
            for (int rg = 0; rg < 4; ++rg)
                h2f[mt * 3 + t][rg] = gelu_f(accT[mt * 3 + t][rg] + bb[rg]) + accS[mt * 3 + t][rg] + sb[rg];
    }
    store_fragmajor(h2f);
    #pragma unroll
    for (int i = 0; i < 12; ++i) { accT[i] = zero; accS[i] = zero; }
    __syncthreads();                                   // B2: h1 ready

    // ================= layer2 + skip2 (K=192, 6 chunks) =================
    #pragma unroll
    for (int ks = 0; ks < 6; ++ks) {
        bf16x8 cw[3], cs[3];
        #pragma unroll
        for (int t = 0; t < 3; ++t) { cw[t] = nxt[t]; cs[t] = nxt[3 + t]; }
        if (ks < 5) {
            #pragma unroll
            for (int t = 0; t < 3; ++t) {
                nxt[t]     = *(const bf16x8*)(W2 + ((f3 + t) * 6 + ks + 1) * 512 + l8);
                nxt[3 + t] = *(const bf16x8*)(S2 + ((f3 + t) * 6 + ks + 1) * 512 + l8);
            }
        } else {
            #pragma unroll
            for (int t = 0; t < 3; ++t)                // prefetch L3 ks0
                nxt[t] = *(const bf16x8*)(W3 + ((f3 + t) * 6 + 0) * 512 + l8);
        }
        compute_dual(Hs, 6, ks, cw, cs);
    }
    // h2 in fp32 registers (precision-critical residual)
    #pragma unroll
    for (int t = 0; t < 3; ++t) {
        int colb = c0 + t * 16 + quad * 4;
        f32x4 bb = *(const f32x4*)(b2 + aH + colb);
        f32x4 sb = *(const f32x4*)(s2b + aH + colb);
        #pragma unroll
        for (int mt = 0; mt < 4; ++mt)
            #pragma unroll
            for (int rg = 0; rg < 4; ++rg)
                h2f[mt * 3 + t][rg] = gelu_f(accT[mt * 3 + t][rg] + bb[rg]) + accS[mt * 3 + t][rg] + sb[rg];
    }
    #pragma unroll
    for (int i = 0; i < 12; ++i) accT[i] = zero;
    __syncthreads();                                   // B3: all h1 reads done
    store_fragmajor(h2f);                              // h2 -> Hs
    __syncthreads();                                   // B4: h2 ready

    // ================= layer3 (K=192) =================
    bf16x8 ow6[6];
    #pragma unroll
    for (int ks = 0; ks < 6; ++ks) {
        bf16x8 cw[3];
        #pragma unroll
        for (int t = 0; t < 3; ++t) cw[t] = nxt[t];
        if (ks < 5) {
            #pragma unroll
            for (int t = 0; t < 3; ++t)
                nxt[t] = *(const bf16x8*)(W3 + ((f3 + t) * 6 + ks + 1) * 512 + l8);
        } else {
            #pragma unroll
            for (int kk = 0; kk < 6; ++kk)             // prefetch OW
                ow6[kk] = *(const bf16x8*)(OWp + kk * 512 + l8);
        }
        compute_single(ks, cw);
    }
    // h3 = (acc + b3 + h2)*hnw + hnb
    #pragma unroll
    for (int t = 0; t < 3; ++t) {
        int colb = c0 + t * 16 + quad * 4;
        f32x4 b3v = *(const f32x4*)(b3  + aH + colb);
        f32x4 nwv = *(const f32x4*)(hnw + aH + colb);
        f32x4 nbv = *(const f32x4*)(hnb + aH + colb);
        #pragma unroll
        for (int mt = 0; mt < 4; ++mt)
            #pragma unroll
            for (int rg = 0; rg < 4; ++rg)
                h2f[mt * 3 + t][rg] = fmaf(accT[mt * 3 + t][rg] + b3v[rg] + h2f[mt * 3 + t][rg],
                                           nwv[rg], nbv[rg]);
    }
    __syncthreads();                                   // B5: all h2 reads done
    store_fragmajor(h2f);                              // h3 -> Hs
    __syncthreads();                                   // B6: h3 ready

    // ================= output (wave wv = row-mtile wv) =================
    {
        f32x4 acco = zero;
        #pragma unroll
        for (int ks = 0; ks < 6; ++ks) {
            bf16x8 av = *(const bf16x8*)(Hs + (wv * 6 + ks) * 512 + l8);
            acco = MFMA(ow6[ks], av, acco);
        }
        if (quad == 0) {                               // o = rg (0..2), rows = wv*16+ln
            float* po = out + ((size_t)a * B_N + row0 + wv * 16 + ln) * O_N;
            po[0] = acco[0] + ob[a * O_N + 0];
            po[1] = acco[1] + ob[a * O_N + 1];
            po[2] = acco[2] + ob[a * O_N + 2];
        }
    }
}

extern "C" void kernel_launch(void* const* d_in, const int* in_sizes, int n_in,
                              void* d_out, int out_size, void* d_ws, size_t ws_size,
                              hipStream_t stream) {
    const float* x   = (const float*)d_in[0];
    const float* inw = (const float*)d_in[1];
    const float* inb = (const float*)d_in[2];
    const float* w1  = (const float*)d_in[3];
    const float* b1  = (const float*)d_in[4];
    const float* w2  = (const float*)d_in[5];
    const float* b2  = (const float*)d_in[6];
    const float* w3  = (const float*)d_in[7];
    const float* b3  = (const float*)d_in[8];
    const float* ow  = (const float*)d_in[9];
    const float* ob  = (const float*)d_in[10];
    const float* s1w = (const float*)d_in[11];
    const float* s1b = (const float*)d_in[12];
    const float* s2w = (const float*)d_in[13];
    const float* s2b = (const float*)d_in[14];
    const float* hnw = (const float*)d_in[15];
    const float* hnb = (const float*)d_in[16];

    __bf16* ws = (__bf16*)d_ws;   // 17.7 MB of d_ws

    prep_kernel<<<dim3(1292), dim3(256), 0, stream>>>(w1, s1w, w2, s2w, w3, ow, ws);

    srek_mfma<<<dim3(A_N * (B_N / 64)), dim3(256), 0, stream>>>(
        x, inw, inb, b1, b2, b3, s1b, s2b, hnw, hnb, ob, ws, (float*)d_out);
}